// Round 1
// baseline (184.198 us; speedup 1.0000x reference)
//
#include <hip/hip_runtime.h>

// MultiHeadedTrilinearAttention, MI355X fp32 implementation.
// B=1, S=128, DIM=768, H=12, W=64, nv=nq=na=16, K=4096 softmax groups of
// contiguous 4096 scores; outputs collapse to marginal sums (trailing dim 1).
// ws usage: 6 * 128*768 floats = 2,359,296 bytes (vp,qp,ap,vo,qo,ao).

#define DIM   768
#define SEQ   128
#define NH    12
#define HW    64
#define PROJ_ELEMS (SEQ * DIM)   // 98304
#define QOUT_OFF   98304
#define AOUT_OFF   196608

// -------- projection GEMM: C[128,768] = A[128,768] @ W[768,768] + b --------
// 32x64 output tiles, 2x4 micro-tile, BK=32, register-prefetch double buffer.
__global__ __launch_bounds__(256) void proj3_kernel(
    const float* __restrict__ A0, const float* __restrict__ A1, const float* __restrict__ A2,
    const float* __restrict__ W0, const float* __restrict__ W1, const float* __restrict__ W2,
    const float* __restrict__ b0, const float* __restrict__ b1, const float* __restrict__ b2,
    float* __restrict__ C0, float* __restrict__ C1, float* __restrict__ C2)
{
    const int gz = blockIdx.z;
    const float* __restrict__ A  = (gz == 0) ? A0 : (gz == 1) ? A1 : A2;
    const float* __restrict__ Wm = (gz == 0) ? W0 : (gz == 1) ? W1 : W2;
    const float* __restrict__ bb = (gz == 0) ? b0 : (gz == 1) ? b1 : b2;
    float* __restrict__ C        = (gz == 0) ? C0 : (gz == 1) ? C1 : C2;

    const int m0 = blockIdx.x * 32;
    const int n0 = blockIdx.y * 64;

    __shared__ float As[2][32][36];   // [buf][k][m], pad 36 -> 2-way max on writes
    __shared__ float Bs[2][32][68];   // [buf][k][n]

    const int t  = threadIdx.x;
    const int ty = t >> 4;            // rows 2ty, 2ty+1
    const int tx = t & 15;            // cols 4tx..4tx+3

    const int ar = t >> 3;            // 0..31  (A stage row)
    const int ac = (t & 7) << 2;      // 0..28  (A stage k)
    const int bk = t >> 4;            // 0..15  (B stage k, and +16)
    const int bc = (t & 15) << 2;     // 0..60  (B stage col)

    float acc[2][4] = {{0.f,0.f,0.f,0.f},{0.f,0.f,0.f,0.f}};

    float4 av  = *(const float4*)&A [(m0 + ar) * DIM + ac];
    float4 bv0 = *(const float4*)&Wm[(bk     ) * DIM + n0 + bc];
    float4 bv1 = *(const float4*)&Wm[(bk + 16) * DIM + n0 + bc];
    As[0][ac + 0][ar] = av.x;
    As[0][ac + 1][ar] = av.y;
    As[0][ac + 2][ar] = av.z;
    As[0][ac + 3][ar] = av.w;
    *(float4*)&Bs[0][bk     ][bc] = bv0;
    *(float4*)&Bs[0][bk + 16][bc] = bv1;

    const int NSTEP = DIM / 32;       // 24
    for (int s = 0; s < NSTEP; ++s) {
        __syncthreads();
        if (s + 1 < NSTEP) {
            const int k0 = (s + 1) * 32;
            av  = *(const float4*)&A [(m0 + ar) * DIM + k0 + ac];
            bv0 = *(const float4*)&Wm[(k0 + bk     ) * DIM + n0 + bc];
            bv1 = *(const float4*)&Wm[(k0 + bk + 16) * DIM + n0 + bc];
        }
        const int cur = s & 1;
        #pragma unroll
        for (int k = 0; k < 32; ++k) {
            const float  a0 = As[cur][k][2 * ty];
            const float  a1 = As[cur][k][2 * ty + 1];
            const float4 b  = *(const float4*)&Bs[cur][k][4 * tx];
            acc[0][0] += a0 * b.x; acc[0][1] += a0 * b.y;
            acc[0][2] += a0 * b.z; acc[0][3] += a0 * b.w;
            acc[1][0] += a1 * b.x; acc[1][1] += a1 * b.y;
            acc[1][2] += a1 * b.z; acc[1][3] += a1 * b.w;
        }
        if (s + 1 < NSTEP) {
            const int nx = cur ^ 1;
            As[nx][ac + 0][ar] = av.x;
            As[nx][ac + 1][ar] = av.y;
            As[nx][ac + 2][ar] = av.z;
            As[nx][ac + 3][ar] = av.w;
            *(float4*)&Bs[nx][bk     ][bc] = bv0;
            *(float4*)&Bs[nx][bk + 16][bc] = bv1;
        }
    }

    const float4 biasv = *(const float4*)&bb[n0 + 4 * tx];
    #pragma unroll
    for (int i = 0; i < 2; ++i) {
        float4 o;
        o.x = acc[i][0] + biasv.x;
        o.y = acc[i][1] + biasv.y;
        o.z = acc[i][2] + biasv.z;
        o.w = acc[i][3] + biasv.w;
        *(float4*)&C[(m0 + 2 * ty + i) * DIM + n0 + 4 * tx] = o;
    }
}

// map flat index of (H,S,W)-ordered "heads view" back into row-major (S,DIM)
__device__ __forceinline__ float fetch_o(const float* __restrict__ p, int idx) {
    // head = idx>>13, token = (idx>>6)&127, w = idx&63
    return p[((idx >> 6) & 127) * DIM + (idx >> 13) * HW + (idx & 63)];
}

// -------- fused scores + group softmax + marginals + outputs --------
// block = (v-token, head); scores s[q][a] (128x128) for this (h,v).
// wave w (64 lanes) == softmax group g = h*512 + v*4 + w  (q in [32w,32w+32)).
__global__ __launch_bounds__(256) void fused_attn_kernel(
    const float* __restrict__ vp, const float* __restrict__ qp, const float* __restrict__ ap,
    const float* __restrict__ vo, const float* __restrict__ qo, const float* __restrict__ ao,
    float* __restrict__ out)
{
    const int vtok = blockIdx.x;   // 0..127
    const int h    = blockIdx.y;   // 0..11

    __shared__ float Al[32][128];  // [k][q] : vh[v,k]*qh[q,k]
    __shared__ float Bl[32][128];  // [k][a] : ah[a,k]

    const int t  = threadIdx.x;
    const int ty = t >> 4;         // q rows 8ty..8ty+7
    const int tx = t & 15;         // a cols 8tx..8tx+7

    const int srow = t >> 1;          // staged token 0..127
    const int w0   = (t & 1) << 4;    // 0 / 16 within 32-wide k phase

    float acc[8][8];
    #pragma unroll
    for (int i = 0; i < 8; ++i)
        #pragma unroll
        for (int j = 0; j < 8; ++j) acc[i][j] = 0.f;

    #pragma unroll
    for (int ph = 0; ph < 2; ++ph) {
        const int base = h * HW + ph * 32 + w0;
        #pragma unroll
        for (int u = 0; u < 4; ++u) {
            const float4 qv = *(const float4*)&qp[srow * DIM + base + 4 * u];
            const float4 vv = *(const float4*)&vp[vtok * DIM + base + 4 * u];
            const float4 aa = *(const float4*)&ap[srow * DIM + base + 4 * u];
            const int wl = w0 + 4 * u;
            Al[wl + 0][srow] = qv.x * vv.x;
            Al[wl + 1][srow] = qv.y * vv.y;
            Al[wl + 2][srow] = qv.z * vv.z;
            Al[wl + 3][srow] = qv.w * vv.w;
            Bl[wl + 0][srow] = aa.x;
            Bl[wl + 1][srow] = aa.y;
            Bl[wl + 2][srow] = aa.z;
            Bl[wl + 3][srow] = aa.w;
        }
        __syncthreads();
        #pragma unroll 4
        for (int k = 0; k < 32; ++k) {
            float af[8], bf[8];
            *(float4*)&af[0] = *(const float4*)&Al[k][8 * ty];
            *(float4*)&af[4] = *(const float4*)&Al[k][8 * ty + 4];
            *(float4*)&bf[0] = *(const float4*)&Bl[k][8 * tx];
            *(float4*)&bf[4] = *(const float4*)&Bl[k][8 * tx + 4];
            #pragma unroll
            for (int i = 0; i < 8; ++i)
                #pragma unroll
                for (int j = 0; j < 8; ++j)
                    acc[i][j] += af[i] * bf[j];
        }
        __syncthreads();
    }

    // scale 1/sqrt(64), wave(=group) max
    float mx = -1e30f;
    #pragma unroll
    for (int i = 0; i < 8; ++i)
        #pragma unroll
        for (int j = 0; j < 8; ++j) {
            acc[i][j] *= 0.125f;
            mx = fmaxf(mx, acc[i][j]);
        }
    #pragma unroll
    for (int d = 1; d < 64; d <<= 1) mx = fmaxf(mx, __shfl_xor(mx, d, 64));

    // exp + per-thread marginal partials
    // group-local q'' = 8*(ty&3)+i, a = 8*tx+c
    // i-bin = q''/2 = 4*(ty&3) + (i>>1)     -> sv[i>>1]
    // j-bin = (q''%2)*8 + a/16 = (i&1)*8 + (tx>>1) -> sq[i&1]
    // k-bin = a%16 = (tx&1)*8 + c           -> sa[c]
    float sv[4] = {0.f, 0.f, 0.f, 0.f};
    float sq[2] = {0.f, 0.f};
    float sa[8] = {0.f, 0.f, 0.f, 0.f, 0.f, 0.f, 0.f, 0.f};
    float tot = 0.f;
    #pragma unroll
    for (int i = 0; i < 8; ++i) {
        float rs = 0.f;
        #pragma unroll
        for (int j = 0; j < 8; ++j) {
            const float e = __expf(acc[i][j] - mx);
            rs += e;
            sa[j] += e;
        }
        sv[i >> 1] += rs;
        sq[i & 1]  += rs;
        tot += rs;
    }

    // wave reductions (all lanes participate; bins differ by lane subsets)
    #pragma unroll
    for (int d = 1; d < 64; d <<= 1) tot += __shfl_xor(tot, d, 64);
    #pragma unroll
    for (int d = 1; d <= 8; d <<= 1) {        // reduce over tx (16 lanes)
        #pragma unroll
        for (int p = 0; p < 4; ++p) sv[p] += __shfl_xor(sv[p], d, 64);
    }
    sq[0] += __shfl_xor(sq[0], 1, 64);  sq[1] += __shfl_xor(sq[1], 1, 64);
    sq[0] += __shfl_xor(sq[0], 16, 64); sq[1] += __shfl_xor(sq[1], 16, 64);
    sq[0] += __shfl_xor(sq[0], 32, 64); sq[1] += __shfl_xor(sq[1], 32, 64);
    #pragma unroll
    for (int dd = 1; dd < 6; ++dd) {          // d = 2,4,8,16,32 (keep tx&1)
        const int d = 1 << dd;
        #pragma unroll
        for (int c = 0; c < 8; ++c) sa[c] += __shfl_xor(sa[c], d, 64);
    }

    const int wv = t >> 6;
    const int l  = t & 63;
    const int g  = h * 512 + vtok * 4 + wv;   // softmax group id
    const int b2 = g / 12;
    const int h2 = g - b2 * 12;
    const float invZ = 1.0f / tot;

    if ((l & 15) == 0) {                      // tx==0 lanes: 16 v-outputs
        const int tyl = l >> 4;
        #pragma unroll
        for (int p = 0; p < 4; ++p) {
            const int bin = tyl * 4 + p;
            const int idx = g * 16 + bin;
            out[(b2 * 16 + bin) * 12 + h2] = sv[p] * invZ * fetch_o(vo, idx);
        }
    }
    if (l < 16 && (l & 1) == 0) {             // 8 lanes: 16 q-outputs
        const int j0 = l >> 1;
        out[QOUT_OFF + (b2 * 16 + j0) * 12 + h2] =
            sq[0] * invZ * fetch_o(qo, g * 16 + j0);
        const int j1 = j0 + 8;
        out[QOUT_OFF + (b2 * 16 + j1) * 12 + h2] =
            sq[1] * invZ * fetch_o(qo, g * 16 + j1);
    }
    if (l < 2) {                              // 2 lanes: 16 a-outputs
        #pragma unroll
        for (int c = 0; c < 8; ++c) {
            const int bin = l * 8 + c;
            const int idx = g * 16 + bin;
            out[AOUT_OFF + (b2 * 16 + bin) * 12 + h2] =
                sa[c] * invZ * fetch_o(ao, idx);
        }
    }
}

extern "C" void kernel_launch(void* const* d_in, const int* in_sizes, int n_in,
                              void* d_out, int out_size, void* d_ws, size_t ws_size,
                              hipStream_t stream)
{
    const float* v   = (const float*)d_in[0];
    const float* q   = (const float*)d_in[1];
    const float* a   = (const float*)d_in[2];
    // d_in[3..5] = masks, unused by the reference forward
    const float* Wv  = (const float*)d_in[6];
    const float* bv  = (const float*)d_in[7];
    const float* Wq  = (const float*)d_in[8];
    const float* bq  = (const float*)d_in[9];
    const float* Wa  = (const float*)d_in[10];
    const float* ba  = (const float*)d_in[11];
    const float* Wvo = (const float*)d_in[12];
    const float* bvo = (const float*)d_in[13];
    const float* Wqo = (const float*)d_in[14];
    const float* bqo = (const float*)d_in[15];
    const float* Wao = (const float*)d_in[16];
    const float* bao = (const float*)d_in[17];

    float* out = (float*)d_out;
    float* ws  = (float*)d_ws;           // needs 6*98304 floats = 2.36 MB
    float* vp = ws + 0 * PROJ_ELEMS;
    float* qp = ws + 1 * PROJ_ELEMS;
    float* ap = ws + 2 * PROJ_ELEMS;
    float* vo = ws + 3 * PROJ_ELEMS;
    float* qo = ws + 4 * PROJ_ELEMS;
    float* ao = ws + 5 * PROJ_ELEMS;

    // first projections: vp = v@Wv+bv, qp = q@Wq+bq, ap = a@Wa+ba
    proj3_kernel<<<dim3(4, 12, 3), 256, 0, stream>>>(
        v, q, a, Wv, Wq, Wa, bv, bq, ba, vp, qp, ap);
    // second projections applied to already-projected tensors (as in source)
    proj3_kernel<<<dim3(4, 12, 3), 256, 0, stream>>>(
        vp, qp, ap, Wvo, Wqo, Wao, bvo, bqo, bao, vo, qo, ao);
    // fused trilinear scores + grouped softmax + marginal outputs
    fused_attn_kernel<<<dim3(SEQ, NH), 256, 0, stream>>>(
        vp, qp, ap, vo, qo, ao, out);
}